// Round 1
// baseline (4439.276 us; speedup 1.0000x reference)
//
#include <hip/hip_runtime.h>

#define N_NODES 50000
#define N_EDGES 800000
#define TOT_E   (N_EDGES + N_NODES)
#define EPS     1e-5f

// folded-weight layout in d_ws (float offsets)
#define OFF_W1 0        // [6][64]
#define OFF_B1 384      // [64]
#define OFF_W2 448      // [64][64]
#define OFF_B2 4544     // [64]
#define OFF_W3 4608     // [64][128]
#define OFF_B3 12800    // [128]
#define WTOT   12928

__device__ __forceinline__ unsigned fkey(float f) {
    unsigned u = __float_as_uint(f);
    return (u & 0x80000000u) ? ~u : (u | 0x80000000u);
}

__global__ void fold_kernel(
    const float* __restrict__ W1, const float* __restrict__ b1,
    const float* __restrict__ g1, const float* __restrict__ be1,
    const float* __restrict__ m1, const float* __restrict__ v1,
    const float* __restrict__ W2, const float* __restrict__ b2,
    const float* __restrict__ g2, const float* __restrict__ be2,
    const float* __restrict__ m2, const float* __restrict__ v2,
    const float* __restrict__ W3, const float* __restrict__ b3,
    const float* __restrict__ g3, const float* __restrict__ be3,
    const float* __restrict__ m3, const float* __restrict__ v3,
    float* __restrict__ wf)
{
    int t = blockIdx.x * blockDim.x + threadIdx.x;
    if (t < 384) {                         // W1 folded
        int j = t % 64;
        float s = g1[j] * rsqrtf(v1[j] + EPS);
        wf[OFF_W1 + t] = W1[t] * s;
    } else if (t < 448) {                  // b1 folded
        int j = t - 384;
        float s = g1[j] * rsqrtf(v1[j] + EPS);
        wf[OFF_B1 + j] = (b1[j] - m1[j]) * s + be1[j];
    } else if (t < 4544) {                 // W2 folded
        int i = t - 448; int j = i % 64;
        float s = g2[j] * rsqrtf(v2[j] + EPS);
        wf[OFF_W2 + i] = W2[i] * s;
    } else if (t < 4608) {                 // b2 folded
        int j = t - 4544;
        float s = g2[j] * rsqrtf(v2[j] + EPS);
        wf[OFF_B2 + j] = (b2[j] - m2[j]) * s + be2[j];
    } else if (t < 12800) {                // W3 folded
        int i = t - 4608; int j = i % 128;
        float s = g3[j] * rsqrtf(v3[j] + EPS);
        wf[OFF_W3 + i] = W3[i] * s;
    } else if (t < WTOT) {                 // b3 folded
        int j = t - 12800;
        float s = g3[j] * rsqrtf(v3[j] + EPS);
        wf[OFF_B3 + j] = (b3[j] - m3[j]) * s + be3[j];
    }
}

__global__ __launch_bounds__(256) void edge_kernel(
    const float* __restrict__ x, const float* __restrict__ pos,
    const int* __restrict__ ei, const float* __restrict__ wf,
    unsigned int* __restrict__ out)
{
    __shared__ float lw[WTOT];
    for (int i = threadIdx.x; i < WTOT; i += 256) lw[i] = wf[i];
    __syncthreads();

    int e = blockIdx.x * 256 + threadIdx.x;
    if (e >= TOT_E) return;

    int src, dst;
    if (e < N_EDGES) { src = ei[e]; dst = ei[N_EDGES + e]; }
    else             { src = dst = e - N_EDGES; }

    float f[6];
    f[0] = x[src * 3 + 0];
    f[1] = x[src * 3 + 1];
    f[2] = x[src * 3 + 2];
    f[3] = pos[src * 3 + 0] - pos[dst * 3 + 0];
    f[4] = pos[src * 3 + 1] - pos[dst * 3 + 1];
    f[5] = pos[src * 3 + 2] - pos[dst * 3 + 2];

    // layer 1: 6 -> 64, ReLU
    float h1[64];
#pragma unroll
    for (int jc = 0; jc < 16; ++jc) {
        float4 acc = *(const float4*)&lw[OFF_B1 + jc * 4];
#pragma unroll
        for (int k = 0; k < 6; ++k) {
            float4 w = *(const float4*)&lw[OFF_W1 + k * 64 + jc * 4];
            acc.x = fmaf(f[k], w.x, acc.x);
            acc.y = fmaf(f[k], w.y, acc.y);
            acc.z = fmaf(f[k], w.z, acc.z);
            acc.w = fmaf(f[k], w.w, acc.w);
        }
        h1[jc * 4 + 0] = fmaxf(acc.x, 0.f);
        h1[jc * 4 + 1] = fmaxf(acc.y, 0.f);
        h1[jc * 4 + 2] = fmaxf(acc.z, 0.f);
        h1[jc * 4 + 3] = fmaxf(acc.w, 0.f);
    }

    // layer 2: 64 -> 64, ReLU
    float h2[64];
#pragma unroll
    for (int jc = 0; jc < 16; ++jc) {
        float4 acc = *(const float4*)&lw[OFF_B2 + jc * 4];
#pragma unroll
        for (int k = 0; k < 64; ++k) {
            float4 w = *(const float4*)&lw[OFF_W2 + k * 64 + jc * 4];
            acc.x = fmaf(h1[k], w.x, acc.x);
            acc.y = fmaf(h1[k], w.y, acc.y);
            acc.z = fmaf(h1[k], w.z, acc.z);
            acc.w = fmaf(h1[k], w.w, acc.w);
        }
        h2[jc * 4 + 0] = fmaxf(acc.x, 0.f);
        h2[jc * 4 + 1] = fmaxf(acc.y, 0.f);
        h2[jc * 4 + 2] = fmaxf(acc.z, 0.f);
        h2[jc * 4 + 3] = fmaxf(acc.w, 0.f);
    }

    // layer 3: 64 -> 128 (no ReLU) + atomic max scatter
    unsigned int* op = out + (size_t)dst * 128;
#pragma unroll
    for (int jc = 0; jc < 32; ++jc) {
        float4 acc = *(const float4*)&lw[OFF_B3 + jc * 4];
#pragma unroll
        for (int k = 0; k < 64; ++k) {
            float4 w = *(const float4*)&lw[OFF_W3 + k * 128 + jc * 4];
            acc.x = fmaf(h2[k], w.x, acc.x);
            acc.y = fmaf(h2[k], w.y, acc.y);
            acc.z = fmaf(h2[k], w.z, acc.z);
            acc.w = fmaf(h2[k], w.w, acc.w);
        }
        atomicMax(op + jc * 4 + 0, fkey(acc.x));
        atomicMax(op + jc * 4 + 1, fkey(acc.y));
        atomicMax(op + jc * 4 + 2, fkey(acc.z));
        atomicMax(op + jc * 4 + 3, fkey(acc.w));
    }
}

__global__ void finalize_kernel(unsigned int* __restrict__ out, int n) {
    int i = blockIdx.x * 256 + threadIdx.x;
    if (i < n) {
        unsigned k = out[i];
        out[i] = (k & 0x80000000u) ? (k ^ 0x80000000u) : ~k;
    }
}

extern "C" void kernel_launch(void* const* d_in, const int* in_sizes, int n_in,
                              void* d_out, int out_size, void* d_ws, size_t ws_size,
                              hipStream_t stream) {
    const float* x   = (const float*)d_in[0];
    const float* pos = (const float*)d_in[1];
    const float* W1  = (const float*)d_in[2];
    const float* b1  = (const float*)d_in[3];
    const float* g1  = (const float*)d_in[4];
    const float* be1 = (const float*)d_in[5];
    const float* m1  = (const float*)d_in[6];
    const float* v1  = (const float*)d_in[7];
    const float* W2  = (const float*)d_in[8];
    const float* b2  = (const float*)d_in[9];
    const float* g2  = (const float*)d_in[10];
    const float* be2 = (const float*)d_in[11];
    const float* m2  = (const float*)d_in[12];
    const float* v2  = (const float*)d_in[13];
    const float* W3  = (const float*)d_in[14];
    const float* b3  = (const float*)d_in[15];
    const float* g3  = (const float*)d_in[16];
    const float* be3 = (const float*)d_in[17];
    const float* m3  = (const float*)d_in[18];
    const float* v3  = (const float*)d_in[19];
    const int*   ei  = (const int*)d_in[20];

    float* wf = (float*)d_ws;
    unsigned int* out_u = (unsigned int*)d_out;

    // init output to key-space minimum (0 < key(-inf))
    hipMemsetAsync(d_out, 0, (size_t)out_size * sizeof(float), stream);

    fold_kernel<<<(WTOT + 255) / 256, 256, 0, stream>>>(
        W1, b1, g1, be1, m1, v1, W2, b2, g2, be2, m2, v2,
        W3, b3, g3, be3, m3, v3, wf);

    edge_kernel<<<(TOT_E + 255) / 256, 256, 0, stream>>>(x, pos, ei, wf, out_u);

    finalize_kernel<<<(out_size + 255) / 256, 256, 0, stream>>>(out_u, out_size);
}

// Round 4
// 1412.583 us; speedup vs baseline: 3.1427x; 3.1427x over previous
//
#include <hip/hip_runtime.h>

#define N_NODES 50000
#define N_EDGES 800000
#define TOT_E   (N_EDGES + N_NODES)
#define EPS     1e-5f

// folded-weight layout (float offsets)
#define OFF_W1 0        // [6][64]
#define OFF_B1 384      // [64]
#define OFF_W2 448      // [64][64]
#define OFF_B2 4544     // [64]
#define OFF_W3 4608     // [64][128]
#define OFF_B3 12800    // [128]
#define WTOT   12928

// workspace byte offsets
#define WS_WF     0
#define WS_CURSOR 51712                      // N_NODES ints
#define WS_EID    251712                     // TOT_E ints (sorted edge ids)
#define WS_NEEDED (WS_EID + TOT_E * 4)       // 3,651,712 bytes

__device__ __forceinline__ unsigned fkey(float f) {
    unsigned u = __float_as_uint(f);
    return (u & 0x80000000u) ? ~u : (u | 0x80000000u);
}

__global__ void fold_kernel(
    const float* __restrict__ W1, const float* __restrict__ b1,
    const float* __restrict__ g1, const float* __restrict__ be1,
    const float* __restrict__ m1, const float* __restrict__ v1,
    const float* __restrict__ W2, const float* __restrict__ b2,
    const float* __restrict__ g2, const float* __restrict__ be2,
    const float* __restrict__ m2, const float* __restrict__ v2,
    const float* __restrict__ W3, const float* __restrict__ b3,
    const float* __restrict__ g3, const float* __restrict__ be3,
    const float* __restrict__ m3, const float* __restrict__ v3,
    float* __restrict__ wf)
{
    int t = blockIdx.x * blockDim.x + threadIdx.x;
    if (t < 384) {
        int j = t % 64;
        float s = g1[j] * rsqrtf(v1[j] + EPS);
        wf[OFF_W1 + t] = W1[t] * s;
    } else if (t < 448) {
        int j = t - 384;
        float s = g1[j] * rsqrtf(v1[j] + EPS);
        wf[OFF_B1 + j] = (b1[j] - m1[j]) * s + be1[j];
    } else if (t < 4544) {
        int i = t - 448; int j = i % 64;
        float s = g2[j] * rsqrtf(v2[j] + EPS);
        wf[OFF_W2 + i] = W2[i] * s;
    } else if (t < 4608) {
        int j = t - 4544;
        float s = g2[j] * rsqrtf(v2[j] + EPS);
        wf[OFF_B2 + j] = (b2[j] - m2[j]) * s + be2[j];
    } else if (t < 12800) {
        int i = t - 4608; int j = i % 128;
        float s = g3[j] * rsqrtf(v3[j] + EPS);
        wf[OFF_W3 + i] = W3[i] * s;
    } else if (t < WTOT) {
        int j = t - 12800;
        float s = g3[j] * rsqrtf(v3[j] + EPS);
        wf[OFF_B3 + j] = (b3[j] - m3[j]) * s + be3[j];
    }
}

__global__ void initcount_kernel(int* __restrict__ cursor) {
    int n = blockIdx.x * 256 + threadIdx.x;
    if (n < N_NODES) cursor[n] = 1;     // self loop
}

__global__ void hist_kernel(const int* __restrict__ ei, int* __restrict__ cursor) {
    int e = blockIdx.x * 256 + threadIdx.x;
    if (e < N_EDGES) atomicAdd(&cursor[ei[N_EDGES + e]], 1);
}

// single-block exclusive scan of N_NODES counts
__global__ __launch_bounds__(1024) void scan_kernel(int* __restrict__ cursor) {
    __shared__ int ssum[1024];
    const int tid = threadIdx.x;
    const int CHUNK = (N_NODES + 1023) / 1024;
    int start = tid * CHUNK;
    int end = min(start + CHUNK, N_NODES);
    int local = 0;
    for (int i = start; i < end; ++i) local += cursor[i];
    ssum[tid] = local;
    __syncthreads();
    for (int off = 1; off < 1024; off <<= 1) {
        int v = 0;
        if (tid >= off) v = ssum[tid - off];
        __syncthreads();
        if (tid >= off) ssum[tid] += v;
        __syncthreads();
    }
    int run = ssum[tid] - local;
    for (int i = start; i < end; ++i) {
        int c = cursor[i];
        cursor[i] = run;
        run += c;
    }
}

__global__ void scatter_kernel(const int* __restrict__ ei, int* __restrict__ cursor,
                               int* __restrict__ eid) {
    int e = blockIdx.x * 256 + threadIdx.x;
    if (e >= TOT_E) return;
    int d = (e < N_EDGES) ? ei[N_EDGES + e] : (e - N_EDGES);
    int p = atomicAdd(&cursor[d], 1);
    eid[p] = e;
}

__global__ __launch_bounds__(256) void gather_kernel(
    const float* __restrict__ x, const float* __restrict__ pos,
    const int* __restrict__ ei, const int* __restrict__ eid,
    const float* __restrict__ wf, unsigned int* __restrict__ out)
{
    __shared__ float lw[WTOT];
    for (int i = threadIdx.x; i < WTOT; i += 256) lw[i] = wf[i];
    __syncthreads();

    const int lane = threadIdx.x & 63;
    const int ebase = (blockIdx.x * 4 + (threadIdx.x >> 6)) * 64;
    const int e = ebase + lane;
    const bool active = e < TOT_E;

    int src = 0, dst = 0;
    if (active) {
        int id = eid[e];
        if (id < N_EDGES) { src = ei[id]; dst = ei[N_EDGES + id]; }
        else              { src = dst = id - N_EDGES; }
    }
    const int nid = active ? dst : (-1 - lane);   // unique negatives for tail lanes

    // ALL shuffles hoisted to full-exec-mask statements. Putting them inside
    // short-circuit &&/|| made them execute with lanes masked off, and
    // ds_bpermute from an inactive source lane returns garbage -> the round-2/3
    // deterministic corruption.
    const int nid0  = __shfl(nid, 0);
    const int nid63 = __shfl(nid, 63);
    const int nm1   = __shfl_up(nid, 1);
    const int nm2   = __shfl_up(nid, 2);
    const int nm4   = __shfl_up(nid, 4);
    const int nm8   = __shfl_up(nid, 8);
    const int nm16  = __shfl_up(nid, 16);
    const int nm32  = __shfl_up(nid, 32);
    const int np1   = __shfl_down(nid, 1);

    // conservative: any segment touching a wave boundary goes through atomics;
    // interior segments provably own their node exclusively (global dst-grouping,
    // and each node's 512B output row is cache-line private).
    const bool boundary = (nid == nid0) || (nid == nid63);
    const bool seg_last = (lane == 63) || (np1 != nid);
    const bool p1  = (lane >= 1)  && (nm1  == nid);
    const bool p2  = (lane >= 2)  && (nm2  == nid);
    const bool p4  = (lane >= 4)  && (nm4  == nid);
    const bool p8  = (lane >= 8)  && (nm8  == nid);
    const bool p16 = (lane >= 16) && (nm16 == nid);
    const bool p32 = (lane >= 32) && (nm32 == nid);

    float f[6];
    f[0] = x[src * 3 + 0];
    f[1] = x[src * 3 + 1];
    f[2] = x[src * 3 + 2];
    f[3] = pos[src * 3 + 0] - pos[dst * 3 + 0];
    f[4] = pos[src * 3 + 1] - pos[dst * 3 + 1];
    f[5] = pos[src * 3 + 2] - pos[dst * 3 + 2];

    // layer 1: 6 -> 64, ReLU
    float h1[64];
#pragma unroll
    for (int jc = 0; jc < 16; ++jc) {
        float4 acc = *(const float4*)&lw[OFF_B1 + jc * 4];
#pragma unroll
        for (int k = 0; k < 6; ++k) {
            float4 w = *(const float4*)&lw[OFF_W1 + k * 64 + jc * 4];
            acc.x = fmaf(f[k], w.x, acc.x);
            acc.y = fmaf(f[k], w.y, acc.y);
            acc.z = fmaf(f[k], w.z, acc.z);
            acc.w = fmaf(f[k], w.w, acc.w);
        }
        h1[jc * 4 + 0] = fmaxf(acc.x, 0.f);
        h1[jc * 4 + 1] = fmaxf(acc.y, 0.f);
        h1[jc * 4 + 2] = fmaxf(acc.z, 0.f);
        h1[jc * 4 + 3] = fmaxf(acc.w, 0.f);
    }

    // layer 2: 64 -> 64, ReLU
    float h2[64];
#pragma unroll
    for (int jc = 0; jc < 16; ++jc) {
        float4 acc = *(const float4*)&lw[OFF_B2 + jc * 4];
#pragma unroll
        for (int k = 0; k < 64; ++k) {
            float4 w = *(const float4*)&lw[OFF_W2 + k * 64 + jc * 4];
            acc.x = fmaf(h1[k], w.x, acc.x);
            acc.y = fmaf(h1[k], w.y, acc.y);
            acc.z = fmaf(h1[k], w.z, acc.z);
            acc.w = fmaf(h1[k], w.w, acc.w);
        }
        h2[jc * 4 + 0] = fmaxf(acc.x, 0.f);
        h2[jc * 4 + 1] = fmaxf(acc.y, 0.f);
        h2[jc * 4 + 2] = fmaxf(acc.z, 0.f);
        h2[jc * 4 + 3] = fmaxf(acc.w, 0.f);
    }

#define SSTEP(S, P)                                                              \
    {                                                                            \
        float ox = __shfl_up(acc.x, S), oy = __shfl_up(acc.y, S);                \
        float oz = __shfl_up(acc.z, S), ow = __shfl_up(acc.w, S);                \
        if (P) {                                                                 \
            acc.x = fmaxf(acc.x, ox); acc.y = fmaxf(acc.y, oy);                  \
            acc.z = fmaxf(acc.z, oz); acc.w = fmaxf(acc.w, ow);                  \
        }                                                                        \
    }

    // layer 3: 64 -> 128 (no ReLU), segmented max within wave, write per node
#pragma unroll
    for (int jc = 0; jc < 32; ++jc) {
        float4 acc = *(const float4*)&lw[OFF_B3 + jc * 4];
#pragma unroll
        for (int k = 0; k < 64; ++k) {
            float4 w = *(const float4*)&lw[OFF_W3 + k * 128 + jc * 4];
            acc.x = fmaf(h2[k], w.x, acc.x);
            acc.y = fmaf(h2[k], w.y, acc.y);
            acc.z = fmaf(h2[k], w.z, acc.z);
            acc.w = fmaf(h2[k], w.w, acc.w);
        }
        SSTEP(1, p1) SSTEP(2, p2) SSTEP(4, p4) SSTEP(8, p8) SSTEP(16, p16) SSTEP(32, p32)
        if (seg_last && active) {
            unsigned int* op = out + (size_t)nid * 128 + jc * 4;
            unsigned kx = fkey(acc.x), ky = fkey(acc.y), kz = fkey(acc.z), kw = fkey(acc.w);
            if (boundary) {
                atomicMax(op + 0, kx); atomicMax(op + 1, ky);
                atomicMax(op + 2, kz); atomicMax(op + 3, kw);
            } else {
                *(uint4*)op = make_uint4(kx, ky, kz, kw);
            }
        }
    }
#undef SSTEP
}

// round-1 proven fallback (pure atomics), used when ws_size is too small
__global__ __launch_bounds__(256) void edge_kernel(
    const float* __restrict__ x, const float* __restrict__ pos,
    const int* __restrict__ ei, const float* __restrict__ wf,
    unsigned int* __restrict__ out)
{
    __shared__ float lw[WTOT];
    for (int i = threadIdx.x; i < WTOT; i += 256) lw[i] = wf[i];
    __syncthreads();

    int e = blockIdx.x * 256 + threadIdx.x;
    if (e >= TOT_E) return;

    int src, dst;
    if (e < N_EDGES) { src = ei[e]; dst = ei[N_EDGES + e]; }
    else             { src = dst = e - N_EDGES; }

    float f[6];
    f[0] = x[src * 3 + 0];
    f[1] = x[src * 3 + 1];
    f[2] = x[src * 3 + 2];
    f[3] = pos[src * 3 + 0] - pos[dst * 3 + 0];
    f[4] = pos[src * 3 + 1] - pos[dst * 3 + 1];
    f[5] = pos[src * 3 + 2] - pos[dst * 3 + 2];

    float h1[64];
#pragma unroll
    for (int jc = 0; jc < 16; ++jc) {
        float4 acc = *(const float4*)&lw[OFF_B1 + jc * 4];
#pragma unroll
        for (int k = 0; k < 6; ++k) {
            float4 w = *(const float4*)&lw[OFF_W1 + k * 64 + jc * 4];
            acc.x = fmaf(f[k], w.x, acc.x);
            acc.y = fmaf(f[k], w.y, acc.y);
            acc.z = fmaf(f[k], w.z, acc.z);
            acc.w = fmaf(f[k], w.w, acc.w);
        }
        h1[jc * 4 + 0] = fmaxf(acc.x, 0.f);
        h1[jc * 4 + 1] = fmaxf(acc.y, 0.f);
        h1[jc * 4 + 2] = fmaxf(acc.z, 0.f);
        h1[jc * 4 + 3] = fmaxf(acc.w, 0.f);
    }

    float h2[64];
#pragma unroll
    for (int jc = 0; jc < 16; ++jc) {
        float4 acc = *(const float4*)&lw[OFF_B2 + jc * 4];
#pragma unroll
        for (int k = 0; k < 64; ++k) {
            float4 w = *(const float4*)&lw[OFF_W2 + k * 64 + jc * 4];
            acc.x = fmaf(h1[k], w.x, acc.x);
            acc.y = fmaf(h1[k], w.y, acc.y);
            acc.z = fmaf(h1[k], w.z, acc.z);
            acc.w = fmaf(h1[k], w.w, acc.w);
        }
        h2[jc * 4 + 0] = fmaxf(acc.x, 0.f);
        h2[jc * 4 + 1] = fmaxf(acc.y, 0.f);
        h2[jc * 4 + 2] = fmaxf(acc.z, 0.f);
        h2[jc * 4 + 3] = fmaxf(acc.w, 0.f);
    }

    unsigned int* op = out + (size_t)dst * 128;
#pragma unroll
    for (int jc = 0; jc < 32; ++jc) {
        float4 acc = *(const float4*)&lw[OFF_B3 + jc * 4];
#pragma unroll
        for (int k = 0; k < 64; ++k) {
            float4 w = *(const float4*)&lw[OFF_W3 + k * 128 + jc * 4];
            acc.x = fmaf(h2[k], w.x, acc.x);
            acc.y = fmaf(h2[k], w.y, acc.y);
            acc.z = fmaf(h2[k], w.z, acc.z);
            acc.w = fmaf(h2[k], w.w, acc.w);
        }
        atomicMax(op + jc * 4 + 0, fkey(acc.x));
        atomicMax(op + jc * 4 + 1, fkey(acc.y));
        atomicMax(op + jc * 4 + 2, fkey(acc.z));
        atomicMax(op + jc * 4 + 3, fkey(acc.w));
    }
}

__global__ void finalize_kernel(unsigned int* __restrict__ out, int n) {
    int i = blockIdx.x * 256 + threadIdx.x;
    if (i < n) {
        unsigned k = out[i];
        out[i] = (k & 0x80000000u) ? (k ^ 0x80000000u) : ~k;
    }
}

extern "C" void kernel_launch(void* const* d_in, const int* in_sizes, int n_in,
                              void* d_out, int out_size, void* d_ws, size_t ws_size,
                              hipStream_t stream) {
    const float* x   = (const float*)d_in[0];
    const float* pos = (const float*)d_in[1];
    const float* W1  = (const float*)d_in[2];
    const float* b1  = (const float*)d_in[3];
    const float* g1  = (const float*)d_in[4];
    const float* be1 = (const float*)d_in[5];
    const float* m1  = (const float*)d_in[6];
    const float* v1  = (const float*)d_in[7];
    const float* W2  = (const float*)d_in[8];
    const float* b2  = (const float*)d_in[9];
    const float* g2  = (const float*)d_in[10];
    const float* be2 = (const float*)d_in[11];
    const float* m2  = (const float*)d_in[12];
    const float* v2  = (const float*)d_in[13];
    const float* W3  = (const float*)d_in[14];
    const float* b3  = (const float*)d_in[15];
    const float* g3  = (const float*)d_in[16];
    const float* be3 = (const float*)d_in[17];
    const float* m3  = (const float*)d_in[18];
    const float* v3  = (const float*)d_in[19];
    const int*   ei  = (const int*)d_in[20];

    char* ws = (char*)d_ws;
    float* wf     = (float*)(ws + WS_WF);
    int*   cursor = (int*)(ws + WS_CURSOR);
    int*   eid    = (int*)(ws + WS_EID);
    unsigned int* out_u = (unsigned int*)d_out;

    hipMemsetAsync(d_out, 0, (size_t)out_size * sizeof(float), stream);

    fold_kernel<<<(WTOT + 255) / 256, 256, 0, stream>>>(
        W1, b1, g1, be1, m1, v1, W2, b2, g2, be2, m2, v2,
        W3, b3, g3, be3, m3, v3, wf);

    if (ws_size >= (size_t)WS_NEEDED) {
        initcount_kernel<<<(N_NODES + 255) / 256, 256, 0, stream>>>(cursor);
        hist_kernel<<<(N_EDGES + 255) / 256, 256, 0, stream>>>(ei, cursor);
        scan_kernel<<<1, 1024, 0, stream>>>(cursor);
        scatter_kernel<<<(TOT_E + 255) / 256, 256, 0, stream>>>(ei, cursor, eid);
        gather_kernel<<<(TOT_E + 255) / 256, 256, 0, stream>>>(x, pos, ei, eid, wf, out_u);
    } else {
        edge_kernel<<<(TOT_E + 255) / 256, 256, 0, stream>>>(x, pos, ei, wf, out_u);
    }

    finalize_kernel<<<(out_size + 255) / 256, 256, 0, stream>>>(out_u, out_size);
}

// Round 5
// 455.489 us; speedup vs baseline: 9.7462x; 3.1012x over previous
//
#include <hip/hip_runtime.h>

#define N_NODES 50000
#define N_EDGES 800000
#define TOT_E   (N_EDGES + N_NODES)
#define EPS     1e-5f

typedef short v8s __attribute__((ext_vector_type(8)));
typedef float v4f __attribute__((ext_vector_type(4)));

// workspace byte offsets
#define WS_W1P    0          // [64 n][32 k] packed u32 (hi16|lo16 bf16)  = 8192 B
#define WS_W2P    8192       // [64 n][64 k] packed u32                  = 16384 B
#define WS_W3P    24576      // [128 n][64 k] packed u32                 = 32768 B
#define WS_B1F    57344      // 64 f32
#define WS_B2F    57600      // 64 f32
#define WS_B3F    57856      // 128 f32
#define WS_CURSOR 58368      // N_NODES ints
#define WS_EID    258368     // TOT_E ints
#define WS_NEEDED (WS_EID + TOT_E * 4)

__device__ __forceinline__ unsigned fkey(float f) {
    unsigned u = __float_as_uint(f);
    return (u & 0x80000000u) ? ~u : (u | 0x80000000u);
}

__device__ __forceinline__ unsigned rne_bf16(float f) {
    unsigned u = __float_as_uint(f);
    return (u + 0x7fffu + ((u >> 16) & 1u)) >> 16;
}

// fp32 -> (bf16 hi, bf16 lo) packed in one u32; hi + lo ~= f to ~2^-17 rel
__device__ __forceinline__ unsigned packsplit(float f) {
    unsigned hi = rne_bf16(f);
    float hif = __uint_as_float(hi << 16);
    unsigned lo = rne_bf16(f - hif);
    return (hi << 16) | lo;
}

__device__ __forceinline__ void unpack8(uint4 a, uint4 b, v8s& hi, v8s& lo) {
    hi = (v8s){(short)(a.x >> 16), (short)(a.y >> 16), (short)(a.z >> 16), (short)(a.w >> 16),
               (short)(b.x >> 16), (short)(b.y >> 16), (short)(b.z >> 16), (short)(b.w >> 16)};
    lo = (v8s){(short)(a.x & 0xffff), (short)(a.y & 0xffff), (short)(a.z & 0xffff), (short)(a.w & 0xffff),
               (short)(b.x & 0xffff), (short)(b.y & 0xffff), (short)(b.z & 0xffff), (short)(b.w & 0xffff)};
}

#define MFMA3(acc, ah, al, bh, bl)                                           \
    acc = __builtin_amdgcn_mfma_f32_16x16x32_bf16(ah, bh, acc, 0, 0, 0);     \
    acc = __builtin_amdgcn_mfma_f32_16x16x32_bf16(ah, bl, acc, 0, 0, 0);     \
    acc = __builtin_amdgcn_mfma_f32_16x16x32_bf16(al, bh, acc, 0, 0, 0);

__global__ void fold_kernel(
    const float* __restrict__ W1, const float* __restrict__ b1,
    const float* __restrict__ g1, const float* __restrict__ be1,
    const float* __restrict__ m1, const float* __restrict__ v1,
    const float* __restrict__ W2, const float* __restrict__ b2,
    const float* __restrict__ g2, const float* __restrict__ be2,
    const float* __restrict__ m2, const float* __restrict__ v2,
    const float* __restrict__ W3, const float* __restrict__ b3,
    const float* __restrict__ g3, const float* __restrict__ be3,
    const float* __restrict__ m3, const float* __restrict__ v3,
    unsigned* __restrict__ w1p, unsigned* __restrict__ w2p, unsigned* __restrict__ w3p,
    float* __restrict__ b1f, float* __restrict__ b2f, float* __restrict__ b3f)
{
    int t = blockIdx.x * blockDim.x + threadIdx.x;
    if (t < 2048) {                       // W1p [n][k], k>=6 zero
        int n = t >> 5, k = t & 31;
        float s = g1[n] * rsqrtf(v1[n] + EPS);
        w1p[t] = (k < 6) ? packsplit(W1[k * 64 + n] * s) : 0u;
    } else if (t < 6144) {                // W2p [n][k]
        int i = t - 2048; int n = i >> 6, k = i & 63;
        float s = g2[n] * rsqrtf(v2[n] + EPS);
        w2p[i] = packsplit(W2[k * 64 + n] * s);
    } else if (t < 14336) {               // W3p [n][k]
        int i = t - 6144; int n = i >> 6, k = i & 63;
        float s = g3[n] * rsqrtf(v3[n] + EPS);
        w3p[i] = packsplit(W3[k * 128 + n] * s);
    } else if (t < 14592) {               // biases
        int i = t - 14336;
        if (i < 64) {
            float s = g1[i] * rsqrtf(v1[i] + EPS);
            b1f[i] = (b1[i] - m1[i]) * s + be1[i];
        } else if (i < 128) {
            int j = i - 64;
            float s = g2[j] * rsqrtf(v2[j] + EPS);
            b2f[j] = (b2[j] - m2[j]) * s + be2[j];
        } else {
            int j = i - 128;
            float s = g3[j] * rsqrtf(v3[j] + EPS);
            b3f[j] = (b3[j] - m3[j]) * s + be3[j];
        }
    }
}

__global__ void initcount_kernel(int* __restrict__ cursor) {
    int n = blockIdx.x * 256 + threadIdx.x;
    if (n < N_NODES) cursor[n] = 1;     // self loop
}

__global__ void hist_kernel(const int* __restrict__ ei, int* __restrict__ cursor) {
    int e = blockIdx.x * 256 + threadIdx.x;
    if (e < N_EDGES) atomicAdd(&cursor[ei[N_EDGES + e]], 1);
}

__global__ __launch_bounds__(1024) void scan_kernel(int* __restrict__ cursor) {
    __shared__ int ssum[1024];
    const int tid = threadIdx.x;
    const int CHUNK = (N_NODES + 1023) / 1024;
    int start = tid * CHUNK;
    int end = min(start + CHUNK, N_NODES);
    int local = 0;
    for (int i = start; i < end; ++i) local += cursor[i];
    ssum[tid] = local;
    __syncthreads();
    for (int off = 1; off < 1024; off <<= 1) {
        int v = 0;
        if (tid >= off) v = ssum[tid - off];
        __syncthreads();
        if (tid >= off) ssum[tid] += v;
        __syncthreads();
    }
    int run = ssum[tid] - local;
    for (int i = start; i < end; ++i) {
        int c = cursor[i];
        cursor[i] = run;
        run += c;
    }
}

__global__ void scatter_kernel(const int* __restrict__ ei, int* __restrict__ cursor,
                               int* __restrict__ eid) {
    int e = blockIdx.x * 256 + threadIdx.x;
    if (e >= TOT_E) return;
    int d = (e < N_EDGES) ? ei[N_EDGES + e] : (e - N_EDGES);
    int p = atomicAdd(&cursor[d], 1);
    eid[p] = e;
}

// one wave per block; 64 edges per wave; MFMA bf16 hi/lo MLP
__global__ __launch_bounds__(64, 2) void gather_kernel(
    const float* __restrict__ x, const float* __restrict__ pos,
    const int* __restrict__ ei, const int* __restrict__ eid,
    const unsigned* __restrict__ w1p, const unsigned* __restrict__ w2p,
    const unsigned* __restrict__ w3p,
    const float* __restrict__ b1f, const float* __restrict__ b2f,
    const float* __restrict__ b3f,
    unsigned int* __restrict__ out)
{
    __shared__ uint4 stg4[64 * 17];          // 17408 B staging (F / H1 / H2 / H3-half)
    unsigned* stg = (unsigned*)stg4;

    const int lane = threadIdx.x;
    const int l15 = lane & 15, g = lane >> 4;
    const int e = blockIdx.x * 64 + lane;
    const bool active = e < TOT_E;

    int src = 0, dst = 0;
    if (active) {
        int id = eid[e];
        if (id < N_EDGES) { src = ei[id]; dst = ei[N_EDGES + id]; }
        else              { src = dst = id - N_EDGES; }
    }
    const int nid = active ? dst : (-1 - lane);

    // hoisted full-exec shuffles (round-4 lesson)
    const int nid0  = __shfl(nid, 0);
    const int nid63 = __shfl(nid, 63);
    const int nm1   = __shfl_up(nid, 1);
    const int nm2   = __shfl_up(nid, 2);
    const int nm4   = __shfl_up(nid, 4);
    const int nm8   = __shfl_up(nid, 8);
    const int nm16  = __shfl_up(nid, 16);
    const int nm32  = __shfl_up(nid, 32);
    const int np1   = __shfl_down(nid, 1);

    const bool boundary = (nid == nid0) || (nid == nid63);
    const bool seg_last = (lane == 63) || (np1 != nid);
    const bool p1  = (lane >= 1)  && (nm1  == nid);
    const bool p2  = (lane >= 2)  && (nm2  == nid);
    const bool p4  = (lane >= 4)  && (nm4  == nid);
    const bool p8  = (lane >= 8)  && (nm8  == nid);
    const bool p16 = (lane >= 16) && (nm16 == nid);
    const bool p32 = (lane >= 32) && (nm32 == nid);

    float f0 = x[src * 3 + 0];
    float f1 = x[src * 3 + 1];
    float f2 = x[src * 3 + 2];
    float f3 = pos[src * 3 + 0] - pos[dst * 3 + 0];
    float f4 = pos[src * 3 + 1] - pos[dst * 3 + 1];
    float f5 = pos[src * 3 + 2] - pos[dst * 3 + 2];

    // ---- stage F: row = lane (edge), stride 36 u32 (9 uint4), k 6..31 zero
    {
        uint4 q0 = make_uint4(packsplit(f0), packsplit(f1), packsplit(f2), packsplit(f3));
        uint4 q1 = make_uint4(packsplit(f4), packsplit(f5), 0u, 0u);
        uint4 z  = make_uint4(0u, 0u, 0u, 0u);
        int b = lane * 9;
        stg4[b + 0] = q0; stg4[b + 1] = q1;
        stg4[b + 2] = z;  stg4[b + 3] = z;
        stg4[b + 4] = z;  stg4[b + 5] = z;
        stg4[b + 6] = z;  stg4[b + 7] = z;
    }

    const uint4* w1q = (const uint4*)w1p;
    const uint4* w2q = (const uint4*)w2p;
    const uint4* w3q = (const uint4*)w3p;

    v8s ah[4][2], al[4][2];

    // ---- layer 1: 64x64 = F(64x32) @ W1(32x64), 3-pass hi/lo
    v4f acc[4][4];
#pragma unroll
    for (int tm = 0; tm < 4; ++tm) {
        uint4 qa = stg4[(16 * tm + l15) * 9 + 2 * g];
        uint4 qb = stg4[(16 * tm + l15) * 9 + 2 * g + 1];
        unpack8(qa, qb, ah[tm][0], al[tm][0]);
    }
#pragma unroll
    for (int tn = 0; tn < 4; ++tn) {
        float bv = b1f[16 * tn + l15];
#pragma unroll
        for (int tm = 0; tm < 4; ++tm) acc[tm][tn] = (v4f){bv, bv, bv, bv};
    }
#pragma unroll
    for (int tn = 0; tn < 4; ++tn) {
        uint4 qa = w1q[(16 * tn + l15) * 8 + 2 * g];
        uint4 qb = w1q[(16 * tn + l15) * 8 + 2 * g + 1];
        v8s bh, bl; unpack8(qa, qb, bh, bl);
#pragma unroll
        for (int tm = 0; tm < 4; ++tm) { MFMA3(acc[tm][tn], ah[tm][0], al[tm][0], bh, bl) }
    }
    // relu + pack + stage H1: [m][k] stride 68 u32
#pragma unroll
    for (int tm = 0; tm < 4; ++tm)
#pragma unroll
        for (int tn = 0; tn < 4; ++tn)
#pragma unroll
            for (int r = 0; r < 4; ++r)
                stg[(16 * tm + 4 * g + r) * 68 + 16 * tn + l15] =
                    packsplit(fmaxf(acc[tm][tn][r], 0.f));

    // ---- layer 2: 64x64 = H1(64x64) @ W2(64x64)
#pragma unroll
    for (int tm = 0; tm < 4; ++tm)
#pragma unroll
        for (int tk = 0; tk < 2; ++tk) {
            uint4 qa = stg4[(16 * tm + l15) * 17 + 8 * tk + 2 * g];
            uint4 qb = stg4[(16 * tm + l15) * 17 + 8 * tk + 2 * g + 1];
            unpack8(qa, qb, ah[tm][tk], al[tm][tk]);
        }
#pragma unroll
    for (int tn = 0; tn < 4; ++tn) {
        float bv = b2f[16 * tn + l15];
#pragma unroll
        for (int tm = 0; tm < 4; ++tm) acc[tm][tn] = (v4f){bv, bv, bv, bv};
    }
#pragma unroll
    for (int tn = 0; tn < 4; ++tn)
#pragma unroll
        for (int tk = 0; tk < 2; ++tk) {
            uint4 qa = w2q[(16 * tn + l15) * 16 + 8 * tk + 2 * g];
            uint4 qb = w2q[(16 * tn + l15) * 16 + 8 * tk + 2 * g + 1];
            v8s bh, bl; unpack8(qa, qb, bh, bl);
#pragma unroll
            for (int tm = 0; tm < 4; ++tm) { MFMA3(acc[tm][tn], ah[tm][tk], al[tm][tk], bh, bl) }
        }
    // relu + pack + stage H2 (same layout as H1)
#pragma unroll
    for (int tm = 0; tm < 4; ++tm)
#pragma unroll
        for (int tn = 0; tn < 4; ++tn)
#pragma unroll
            for (int r = 0; r < 4; ++r)
                stg[(16 * tm + 4 * g + r) * 68 + 16 * tn + l15] =
                    packsplit(fmaxf(acc[tm][tn][r], 0.f));

    // ---- layer 3: H2(64x64) @ W3(64x128), two 64-col halves, fused epilogue
#pragma unroll
    for (int tm = 0; tm < 4; ++tm)
#pragma unroll
        for (int tk = 0; tk < 2; ++tk) {
            uint4 qa = stg4[(16 * tm + l15) * 17 + 8 * tk + 2 * g];
            uint4 qb = stg4[(16 * tm + l15) * 17 + 8 * tk + 2 * g + 1];
            unpack8(qa, qb, ah[tm][tk], al[tm][tk]);
        }

#define SSTEP(S, P)                                                              \
    {                                                                            \
        float ox = __shfl_up(vx, S), oy = __shfl_up(vy, S);                      \
        float oz = __shfl_up(vz, S), ow = __shfl_up(vw, S);                      \
        if (P) {                                                                 \
            vx = fmaxf(vx, ox); vy = fmaxf(vy, oy);                              \
            vz = fmaxf(vz, oz); vw = fmaxf(vw, ow);                              \
        }                                                                        \
    }

#pragma unroll
    for (int h = 0; h < 2; ++h) {
#pragma unroll
        for (int tn = 0; tn < 4; ++tn) {
            float bv = b3f[64 * h + 16 * tn + l15];
#pragma unroll
            for (int tm = 0; tm < 4; ++tm) acc[tm][tn] = (v4f){bv, bv, bv, bv};
        }
#pragma unroll
        for (int tn = 0; tn < 4; ++tn)
#pragma unroll
            for (int tk = 0; tk < 2; ++tk) {
                uint4 qa = w3q[(16 * (4 * h + tn) + l15) * 16 + 8 * tk + 2 * g];
                uint4 qb = w3q[(16 * (4 * h + tn) + l15) * 16 + 8 * tk + 2 * g + 1];
                v8s bh, bl; unpack8(qa, qb, bh, bl);
#pragma unroll
                for (int tm = 0; tm < 4; ++tm) { MFMA3(acc[tm][tn], ah[tm][tk], al[tm][tk], bh, bl) }
            }
        // stage H3-half as f32 bits: [m][c] stride 68
#pragma unroll
        for (int tm = 0; tm < 4; ++tm)
#pragma unroll
            for (int tn = 0; tn < 4; ++tn)
#pragma unroll
                for (int r = 0; r < 4; ++r)
                    stg[(16 * tm + 4 * g + r) * 68 + 16 * tn + l15] =
                        __float_as_uint(acc[tm][tn][r]);

        // epilogue: lane reads its edge's row, segmented max, write/atomic
#pragma unroll
        for (int jc = 0; jc < 16; ++jc) {
            uint4 q = stg4[lane * 17 + jc];
            float vx = __uint_as_float(q.x), vy = __uint_as_float(q.y);
            float vz = __uint_as_float(q.z), vw = __uint_as_float(q.w);
            SSTEP(1, p1) SSTEP(2, p2) SSTEP(4, p4) SSTEP(8, p8) SSTEP(16, p16) SSTEP(32, p32)
            if (seg_last && active) {
                unsigned int* op = out + (size_t)nid * 128 + h * 64 + jc * 4;
                unsigned kx = fkey(vx), ky = fkey(vy), kz = fkey(vz), kw = fkey(vw);
                if (boundary) {
                    atomicMax(op + 0, kx); atomicMax(op + 1, ky);
                    atomicMax(op + 2, kz); atomicMax(op + 3, kw);
                } else {
                    *(uint4*)op = make_uint4(kx, ky, kz, kw);
                }
            }
        }
    }
#undef SSTEP
}

__global__ void finalize_kernel(unsigned int* __restrict__ out, int n) {
    int i = blockIdx.x * 256 + threadIdx.x;
    if (i < n) {
        unsigned k = out[i];
        out[i] = (k & 0x80000000u) ? (k ^ 0x80000000u) : ~k;
    }
}

extern "C" void kernel_launch(void* const* d_in, const int* in_sizes, int n_in,
                              void* d_out, int out_size, void* d_ws, size_t ws_size,
                              hipStream_t stream) {
    const float* x   = (const float*)d_in[0];
    const float* pos = (const float*)d_in[1];
    const float* W1  = (const float*)d_in[2];
    const float* b1  = (const float*)d_in[3];
    const float* g1  = (const float*)d_in[4];
    const float* be1 = (const float*)d_in[5];
    const float* m1  = (const float*)d_in[6];
    const float* v1  = (const float*)d_in[7];
    const float* W2  = (const float*)d_in[8];
    const float* b2  = (const float*)d_in[9];
    const float* g2  = (const float*)d_in[10];
    const float* be2 = (const float*)d_in[11];
    const float* m2  = (const float*)d_in[12];
    const float* v2  = (const float*)d_in[13];
    const float* W3  = (const float*)d_in[14];
    const float* b3  = (const float*)d_in[15];
    const float* g3  = (const float*)d_in[16];
    const float* be3 = (const float*)d_in[17];
    const float* m3  = (const float*)d_in[18];
    const float* v3  = (const float*)d_in[19];
    const int*   ei  = (const int*)d_in[20];

    char* ws = (char*)d_ws;
    unsigned* w1p = (unsigned*)(ws + WS_W1P);
    unsigned* w2p = (unsigned*)(ws + WS_W2P);
    unsigned* w3p = (unsigned*)(ws + WS_W3P);
    float* b1f = (float*)(ws + WS_B1F);
    float* b2f = (float*)(ws + WS_B2F);
    float* b3f = (float*)(ws + WS_B3F);
    int* cursor = (int*)(ws + WS_CURSOR);
    int* eid    = (int*)(ws + WS_EID);
    unsigned int* out_u = (unsigned int*)d_out;

    hipMemsetAsync(d_out, 0, (size_t)out_size * sizeof(float), stream);

    fold_kernel<<<57, 256, 0, stream>>>(
        W1, b1, g1, be1, m1, v1, W2, b2, g2, be2, m2, v2,
        W3, b3, g3, be3, m3, v3, w1p, w2p, w3p, b1f, b2f, b3f);

    initcount_kernel<<<(N_NODES + 255) / 256, 256, 0, stream>>>(cursor);
    hist_kernel<<<(N_EDGES + 255) / 256, 256, 0, stream>>>(ei, cursor);
    scan_kernel<<<1, 1024, 0, stream>>>(cursor);
    scatter_kernel<<<(TOT_E + 255) / 256, 256, 0, stream>>>(ei, cursor, eid);

    gather_kernel<<<(TOT_E + 63) / 64, 64, 0, stream>>>(
        x, pos, ei, eid, w1p, w2p, w3p, b1f, b2f, b3f, out_u);

    finalize_kernel<<<(out_size + 255) / 256, 256, 0, stream>>>(out_u, out_size);
}

// Round 6
// 337.678 us; speedup vs baseline: 13.1465x; 1.3489x over previous
//
#include <hip/hip_runtime.h>

#define N_NODES 50000
#define N_EDGES 800000
#define TOT_E   (N_EDGES + N_NODES)
#define EPS     1e-5f

typedef short v8s __attribute__((ext_vector_type(8)));
typedef float v4f __attribute__((ext_vector_type(4)));

// workspace byte offsets
#define WS_W1P    0          // [64 n][32 k] packed u32 (hi16|lo16 bf16)  = 8192 B
#define WS_W2P    8192       // [64 n][64 k] packed u32                  = 16384 B
#define WS_W3P    24576      // [128 n][64 k] packed u32                 = 32768 B
#define WS_B1F    57344      // 64 f32
#define WS_B2F    57600      // 64 f32
#define WS_B3F    57856      // 128 f32
#define WS_CURSOR 58368      // N_NODES ints
#define WS_EID    258368     // TOT_E ints
#define WS_NEEDED (WS_EID + TOT_E * 4)

__device__ __forceinline__ unsigned rne_bf16(float f) {
    unsigned u = __float_as_uint(f);
    return (u + 0x7fffu + ((u >> 16) & 1u)) >> 16;
}

// fp32 -> (bf16 hi, bf16 lo) packed in one u32; hi + lo ~= f to ~2^-17 rel
__device__ __forceinline__ unsigned packsplit(float f) {
    unsigned hi = rne_bf16(f);
    float hif = __uint_as_float(hi << 16);
    unsigned lo = rne_bf16(f - hif);
    return (hi << 16) | lo;
}

__device__ __forceinline__ void unpack8(uint4 a, uint4 b, v8s& hi, v8s& lo) {
    hi = (v8s){(short)(a.x >> 16), (short)(a.y >> 16), (short)(a.z >> 16), (short)(a.w >> 16),
               (short)(b.x >> 16), (short)(b.y >> 16), (short)(b.z >> 16), (short)(b.w >> 16)};
    lo = (v8s){(short)(a.x & 0xffff), (short)(a.y & 0xffff), (short)(a.z & 0xffff), (short)(a.w & 0xffff),
               (short)(b.x & 0xffff), (short)(b.y & 0xffff), (short)(b.z & 0xffff), (short)(b.w & 0xffff)};
}

#define MFMA3(acc, ah, al, bh, bl)                                           \
    acc = __builtin_amdgcn_mfma_f32_16x16x32_bf16(ah, bh, acc, 0, 0, 0);     \
    acc = __builtin_amdgcn_mfma_f32_16x16x32_bf16(ah, bl, acc, 0, 0, 0);     \
    acc = __builtin_amdgcn_mfma_f32_16x16x32_bf16(al, bh, acc, 0, 0, 0);

__global__ void fold_kernel(
    const float* __restrict__ W1, const float* __restrict__ b1,
    const float* __restrict__ g1, const float* __restrict__ be1,
    const float* __restrict__ m1, const float* __restrict__ v1,
    const float* __restrict__ W2, const float* __restrict__ b2,
    const float* __restrict__ g2, const float* __restrict__ be2,
    const float* __restrict__ m2, const float* __restrict__ v2,
    const float* __restrict__ W3, const float* __restrict__ b3,
    const float* __restrict__ g3, const float* __restrict__ be3,
    const float* __restrict__ m3, const float* __restrict__ v3,
    unsigned* __restrict__ w1p, unsigned* __restrict__ w2p, unsigned* __restrict__ w3p,
    float* __restrict__ b1f, float* __restrict__ b2f, float* __restrict__ b3f)
{
    int t = blockIdx.x * blockDim.x + threadIdx.x;
    if (t < 2048) {                       // W1p [n][k], k>=6 zero
        int n = t >> 5, k = t & 31;
        float s = g1[n] * rsqrtf(v1[n] + EPS);
        w1p[t] = (k < 6) ? packsplit(W1[k * 64 + n] * s) : 0u;
    } else if (t < 6144) {                // W2p [n][k]
        int i = t - 2048; int n = i >> 6, k = i & 63;
        float s = g2[n] * rsqrtf(v2[n] + EPS);
        w2p[i] = packsplit(W2[k * 64 + n] * s);
    } else if (t < 14336) {               // W3p [n][k]
        int i = t - 6144; int n = i >> 6, k = i & 63;
        float s = g3[n] * rsqrtf(v3[n] + EPS);
        w3p[i] = packsplit(W3[k * 128 + n] * s);
    } else if (t < 14592) {               // biases
        int i = t - 14336;
        if (i < 64) {
            float s = g1[i] * rsqrtf(v1[i] + EPS);
            b1f[i] = (b1[i] - m1[i]) * s + be1[i];
        } else if (i < 128) {
            int j = i - 64;
            float s = g2[j] * rsqrtf(v2[j] + EPS);
            b2f[j] = (b2[j] - m2[j]) * s + be2[j];
        } else {
            int j = i - 128;
            float s = g3[j] * rsqrtf(v3[j] + EPS);
            b3f[j] = (b3[j] - m3[j]) * s + be3[j];
        }
    }
}

// cursor = 1 (self loop) and out = -inf in one pass
__global__ void init_kernel(int* __restrict__ cursor, uint4* __restrict__ out4) {
    int i = blockIdx.x * 256 + threadIdx.x;
    if (i < N_NODES) cursor[i] = 1;
    if (i < (N_NODES * 128) / 4)
        out4[i] = make_uint4(0xFF800000u, 0xFF800000u, 0xFF800000u, 0xFF800000u);
}

__global__ void hist_kernel(const int* __restrict__ ei, int* __restrict__ cursor) {
    int e = blockIdx.x * 256 + threadIdx.x;
    if (e < N_EDGES) atomicAdd(&cursor[ei[N_EDGES + e]], 1);
}

__global__ __launch_bounds__(1024) void scan_kernel(int* __restrict__ cursor) {
    __shared__ int ssum[1024];
    const int tid = threadIdx.x;
    const int CHUNK = (N_NODES + 1023) / 1024;
    int start = tid * CHUNK;
    int end = min(start + CHUNK, N_NODES);
    int local = 0;
    for (int i = start; i < end; ++i) local += cursor[i];
    ssum[tid] = local;
    __syncthreads();
    for (int off = 1; off < 1024; off <<= 1) {
        int v = 0;
        if (tid >= off) v = ssum[tid - off];
        __syncthreads();
        if (tid >= off) ssum[tid] += v;
        __syncthreads();
    }
    int run = ssum[tid] - local;
    for (int i = start; i < end; ++i) {
        int c = cursor[i];
        cursor[i] = run;
        run += c;
    }
}

__global__ void scatter_kernel(const int* __restrict__ ei, int* __restrict__ cursor,
                               int* __restrict__ eid) {
    int e = blockIdx.x * 256 + threadIdx.x;
    if (e >= TOT_E) return;
    int d = (e < N_EDGES) ? ei[N_EDGES + e] : (e - N_EDGES);
    int p = atomicAdd(&cursor[d], 1);
    eid[p] = e;
}

// one wave per block; 64 edges per wave; MFMA bf16 hi/lo MLP;
// epilogue: lane = feature, serial uniform walk over the 64 staged edges.
__global__ __launch_bounds__(64, 2) void gather_kernel(
    const float* __restrict__ x, const float* __restrict__ pos,
    const int* __restrict__ ei, const int* __restrict__ eid,
    const unsigned* __restrict__ w1p, const unsigned* __restrict__ w2p,
    const unsigned* __restrict__ w3p,
    const float* __restrict__ b1f, const float* __restrict__ b2f,
    const float* __restrict__ b3f,
    float* __restrict__ out)
{
    __shared__ uint4 stg4[64 * 17];          // 17408 B staging (F / H1 / H2 / H3-half)
    unsigned* stg = (unsigned*)stg4;

    const int lane = threadIdx.x;
    const int l15 = lane & 15, g = lane >> 4;
    const int e = blockIdx.x * 64 + lane;
    const bool active = e < TOT_E;

    int src = 0, dst = 0;
    if (active) {
        int id = eid[e];
        if (id < N_EDGES) { src = ei[id]; dst = ei[N_EDGES + id]; }
        else              { src = dst = id - N_EDGES; }
    }
    const int nid = active ? dst : (-1 - lane);   // unique negative keys for tail lanes

    // full-exec-mask shuffles only (round-4 lesson)
    const int np1 = __shfl_down(nid, 1);
    const bool seg_last = (lane == 63) || (np1 != nid);
    const unsigned long long segmask = __ballot(seg_last);  // bit e: edge e ends a segment

    float f0 = x[src * 3 + 0];
    float f1 = x[src * 3 + 1];
    float f2 = x[src * 3 + 2];
    float f3 = pos[src * 3 + 0] - pos[dst * 3 + 0];
    float f4 = pos[src * 3 + 1] - pos[dst * 3 + 1];
    float f5 = pos[src * 3 + 2] - pos[dst * 3 + 2];

    // ---- stage F: row = lane (edge), 9 uint4 stride, k 6..31 zero
    {
        uint4 q0 = make_uint4(packsplit(f0), packsplit(f1), packsplit(f2), packsplit(f3));
        uint4 q1 = make_uint4(packsplit(f4), packsplit(f5), 0u, 0u);
        uint4 z  = make_uint4(0u, 0u, 0u, 0u);
        int b = lane * 9;
        stg4[b + 0] = q0; stg4[b + 1] = q1;
        stg4[b + 2] = z;  stg4[b + 3] = z;
        stg4[b + 4] = z;  stg4[b + 5] = z;
        stg4[b + 6] = z;  stg4[b + 7] = z;
    }

    const uint4* w1q = (const uint4*)w1p;
    const uint4* w2q = (const uint4*)w2p;
    const uint4* w3q = (const uint4*)w3p;

    v8s ah[4][2], al[4][2];

    // ---- layer 1: 64x64 = F(64x32) @ W1(32x64), 3-pass hi/lo
    v4f acc[4][4];
#pragma unroll
    for (int tm = 0; tm < 4; ++tm) {
        uint4 qa = stg4[(16 * tm + l15) * 9 + 2 * g];
        uint4 qb = stg4[(16 * tm + l15) * 9 + 2 * g + 1];
        unpack8(qa, qb, ah[tm][0], al[tm][0]);
    }
#pragma unroll
    for (int tn = 0; tn < 4; ++tn) {
        float bv = b1f[16 * tn + l15];
#pragma unroll
        for (int tm = 0; tm < 4; ++tm) acc[tm][tn] = (v4f){bv, bv, bv, bv};
    }
#pragma unroll
    for (int tn = 0; tn < 4; ++tn) {
        uint4 qa = w1q[(16 * tn + l15) * 8 + 2 * g];
        uint4 qb = w1q[(16 * tn + l15) * 8 + 2 * g + 1];
        v8s bh, bl; unpack8(qa, qb, bh, bl);
#pragma unroll
        for (int tm = 0; tm < 4; ++tm) { MFMA3(acc[tm][tn], ah[tm][0], al[tm][0], bh, bl) }
    }
    // relu + pack + stage H1: [m][k] stride 68 u32
#pragma unroll
    for (int tm = 0; tm < 4; ++tm)
#pragma unroll
        for (int tn = 0; tn < 4; ++tn)
#pragma unroll
            for (int r = 0; r < 4; ++r)
                stg[(16 * tm + 4 * g + r) * 68 + 16 * tn + l15] =
                    packsplit(fmaxf(acc[tm][tn][r], 0.f));

    // ---- layer 2: 64x64 = H1(64x64) @ W2(64x64)
#pragma unroll
    for (int tm = 0; tm < 4; ++tm)
#pragma unroll
        for (int tk = 0; tk < 2; ++tk) {
            uint4 qa = stg4[(16 * tm + l15) * 17 + 8 * tk + 2 * g];
            uint4 qb = stg4[(16 * tm + l15) * 17 + 8 * tk + 2 * g + 1];
            unpack8(qa, qb, ah[tm][tk], al[tm][tk]);
        }
#pragma unroll
    for (int tn = 0; tn < 4; ++tn) {
        float bv = b2f[16 * tn + l15];
#pragma unroll
        for (int tm = 0; tm < 4; ++tm) acc[tm][tn] = (v4f){bv, bv, bv, bv};
    }
#pragma unroll
    for (int tn = 0; tn < 4; ++tn)
#pragma unroll
        for (int tk = 0; tk < 2; ++tk) {
            uint4 qa = w2q[(16 * tn + l15) * 16 + 8 * tk + 2 * g];
            uint4 qb = w2q[(16 * tn + l15) * 16 + 8 * tk + 2 * g + 1];
            v8s bh, bl; unpack8(qa, qb, bh, bl);
#pragma unroll
            for (int tm = 0; tm < 4; ++tm) { MFMA3(acc[tm][tn], ah[tm][tk], al[tm][tk], bh, bl) }
        }
    // relu + pack + stage H2 (same layout as H1)
#pragma unroll
    for (int tm = 0; tm < 4; ++tm)
#pragma unroll
        for (int tn = 0; tn < 4; ++tn)
#pragma unroll
            for (int r = 0; r < 4; ++r)
                stg[(16 * tm + 4 * g + r) * 68 + 16 * tn + l15] =
                    packsplit(fmaxf(acc[tm][tn][r], 0.f));

    // ---- layer 3: H2(64x64) @ W3(64x128), two 64-col halves, fused epilogue
#pragma unroll
    for (int tm = 0; tm < 4; ++tm)
#pragma unroll
        for (int tk = 0; tk < 2; ++tk) {
            uint4 qa = stg4[(16 * tm + l15) * 17 + 8 * tk + 2 * g];
            uint4 qb = stg4[(16 * tm + l15) * 17 + 8 * tk + 2 * g + 1];
            unpack8(qa, qb, ah[tm][tk], al[tm][tk]);
        }

#pragma unroll
    for (int h = 0; h < 2; ++h) {
#pragma unroll
        for (int tn = 0; tn < 4; ++tn) {
            float bv = b3f[64 * h + 16 * tn + l15];
#pragma unroll
            for (int tm = 0; tm < 4; ++tm) acc[tm][tn] = (v4f){bv, bv, bv, bv};
        }
#pragma unroll
        for (int tn = 0; tn < 4; ++tn)
#pragma unroll
            for (int tk = 0; tk < 2; ++tk) {
                uint4 qa = w3q[(16 * (4 * h + tn) + l15) * 16 + 8 * tk + 2 * g];
                uint4 qb = w3q[(16 * (4 * h + tn) + l15) * 16 + 8 * tk + 2 * g + 1];
                v8s bh, bl; unpack8(qa, qb, bh, bl);
#pragma unroll
                for (int tm = 0; tm < 4; ++tm) { MFMA3(acc[tm][tn], ah[tm][tk], al[tm][tk], bh, bl) }
            }
        // stage H3-half as f32 bits: [edge][c] stride 68
#pragma unroll
        for (int tm = 0; tm < 4; ++tm)
#pragma unroll
            for (int tn = 0; tn < 4; ++tn)
#pragma unroll
                for (int r = 0; r < 4; ++r)
                    stg[(16 * tm + 4 * g + r) * 68 + 16 * tn + l15] =
                        __float_as_uint(acc[tm][tn][r]);

        // ---- serial uniform epilogue: lane = feature (h*64+lane); walk 64 edges.
        // All control flow is wave-uniform (segmask bits, readlane'd nid).
        {
            float running = -__builtin_inff();
            bool first_flush = true;
#pragma unroll
            for (int e2 = 0; e2 < 64; ++e2) {
                float val = __uint_as_float(stg[e2 * 68 + lane]);
                running = fmaxf(running, val);
                if ((segmask >> e2) & 1ull) {
                    int n = __builtin_amdgcn_readlane(nid, e2);
                    if (n >= 0) {
                        float* op = out + (size_t)n * 128 + h * 64 + lane;
                        // first/last segment of the wave may span wave boundaries
                        if (first_flush || e2 == 63) atomicMax(op, running);
                        else *op = running;
                    }
                    first_flush = false;
                    running = -__builtin_inff();
                }
            }
        }
    }
}

extern "C" void kernel_launch(void* const* d_in, const int* in_sizes, int n_in,
                              void* d_out, int out_size, void* d_ws, size_t ws_size,
                              hipStream_t stream) {
    const float* x   = (const float*)d_in[0];
    const float* pos = (const float*)d_in[1];
    const float* W1  = (const float*)d_in[2];
    const float* b1  = (const float*)d_in[3];
    const float* g1  = (const float*)d_in[4];
    const float* be1 = (const float*)d_in[5];
    const float* m1  = (const float*)d_in[6];
    const float* v1  = (const float*)d_in[7];
    const float* W2  = (const float*)d_in[8];
    const float* b2  = (const float*)d_in[9];
    const float* g2  = (const float*)d_in[10];
    const float* be2 = (const float*)d_in[11];
    const float* m2  = (const float*)d_in[12];
    const float* v2  = (const float*)d_in[13];
    const float* W3  = (const float*)d_in[14];
    const float* b3  = (const float*)d_in[15];
    const float* g3  = (const float*)d_in[16];
    const float* be3 = (const float*)d_in[17];
    const float* m3  = (const float*)d_in[18];
    const float* v3  = (const float*)d_in[19];
    const int*   ei  = (const int*)d_in[20];

    char* ws = (char*)d_ws;
    unsigned* w1p = (unsigned*)(ws + WS_W1P);
    unsigned* w2p = (unsigned*)(ws + WS_W2P);
    unsigned* w3p = (unsigned*)(ws + WS_W3P);
    float* b1f = (float*)(ws + WS_B1F);
    float* b2f = (float*)(ws + WS_B2F);
    float* b3f = (float*)(ws + WS_B3F);
    int* cursor = (int*)(ws + WS_CURSOR);
    int* eid    = (int*)(ws + WS_EID);
    float* outf = (float*)d_out;

    fold_kernel<<<57, 256, 0, stream>>>(
        W1, b1, g1, be1, m1, v1, W2, b2, g2, be2, m2, v2,
        W3, b3, g3, be3, m3, v3, w1p, w2p, w3p, b1f, b2f, b3f);

    // cursor=1 + out=-inf fused (1.6M threads covers both)
    init_kernel<<<(N_NODES * 128 / 4 + 255) / 256, 256, 0, stream>>>(
        cursor, (uint4*)d_out);

    hist_kernel<<<(N_EDGES + 255) / 256, 256, 0, stream>>>(ei, cursor);
    scan_kernel<<<1, 1024, 0, stream>>>(cursor);
    scatter_kernel<<<(TOT_E + 255) / 256, 256, 0, stream>>>(ei, cursor, eid);

    gather_kernel<<<(TOT_E + 63) / 64, 64, 0, stream>>>(
        x, pos, ei, eid, w1p, w2p, w3p, b1f, b2f, b3f, outf);
}